// Round 10
// baseline (16.630 us; speedup 1.0000x reference)
//
#include <hip/hip_runtime.h>

// ParallelLatticeModel v10: break GPU-wide phase-lock. 1024 blocks x 2
// row-tiles with x-prefetch (waves desync across loop phases -> pipes
// overlap); k1 B-frags and k2 quads hoisted to REGISTERS from global
// (L2-hot, once per block) so the loop body's LDS traffic is only
// calibration (96B/thread) + the wave-private A-frag exchange (64B/thread).
// Calibration = v8's proven binary search; MFMA layouts test-verified v3-v9.
//
// B=131072 rows, D=16 features, 4 lattices x 4 dims (16 corners), E=24 cols,
// K=16 calibration keypoints.
//
// Block = 256 threads = 4 waves; tile = 64 rows; wave wv owns rows 16wv..+15.
// Per tile: lane = r15 + 16q calibrates features 4q..4q+3 of row r15 (binary
// search in padded sKp + affine sAff entry), builds lattice-q corner weights,
// exchanges fp16 A-frags through padded wave-private sW (lgkmcnt fence only),
// then 4 lattices x 2 N-tiles of v_mfma_f32_16x16x16_f16 and the packed
// layer-2 lerp chain. C layout: col=lane&15, row=4*(lane>>4)+reg.

typedef _Float16 f16x4 __attribute__((ext_vector_type(4)));
typedef float f32x4 __attribute__((ext_vector_type(4)));
typedef float f32x2 __attribute__((ext_vector_type(2)));

namespace {
constexpr int kD = 16, kE = 24, kK = 16, kNV = 16;
constexpr int kThreads = 256;
constexpr int kRPT = 64;             // rows per tile
constexpr int kTPB = 2;              // tiles per block
constexpr int kKpS  = 17;            // sKp row stride (floats)  - odd pad
constexpr int kAffS = 17;            // sAff row stride (f32x2)  - odd pad
constexpr int kWS   = 67;            // sW region stride (f16x4) - odd pad
}

static __device__ __forceinline__ f32x2 fma2(f32x2 a, f32x2 b, f32x2 c) {
#if __has_builtin(__builtin_elementwise_fma)
    return __builtin_elementwise_fma(a, b, c);
#else
    return (f32x2){fmaf(a[0], b[0], c[0]), fmaf(a[1], b[1], c[1])};
#endif
}
static __device__ __forceinline__ f32x2 fma2s(f32x2 a, float b, float c) {
    return fma2(a, (f32x2){b, b}, (f32x2){c, c});
}
static __device__ __forceinline__ f32x2 clamp01(f32x2 v) {
    return (f32x2){fminf(fmaxf(v[0], 0.f), 1.f), fminf(fmaxf(v[1], 0.f), 1.f)};
}

__global__ __launch_bounds__(kThreads, 4) void lattice_fwd(
    const float* __restrict__ x,
    const float* __restrict__ cal_kp,    // [D][K]
    const float* __restrict__ cal_vals,  // [D][K]
    const float* __restrict__ k1,        // [E][4][16]
    const float* __restrict__ k2,        // [E][16]
    float* __restrict__ out)             // [B][E]
{
    __shared__ float sKp[kD * kKpS];     // padded kp rows, +INF sentinel 1.1KB
    __shared__ f32x2 sAff[kD * kAffS];   // {slope, intercept} padded     2.1KB
    __shared__ f16x4 sW[16 * kWS];       // [wave*lattice padded][lane]   8.4KB

    const int tid  = threadIdx.x;
    const int lane = tid & 63;
    const int wv   = __builtin_amdgcn_readfirstlane(tid >> 6);   // 0..3
    const int q    = lane >> 4;          // feature-quarter / lattice
    const int r15  = lane & 15;          // row in tile (ph1) / col e (ph2)
    const int g    = lane >> 4;          // k-slice for B-frags (same as q)

    // ---------------- per-lane table registers from global (L2-hot) --------
    // e per n-tile; clamp to 23 for loads (values unused, stores masked;
    // column independence of GEMM keeps garbage confined to masked cols)
    const int eN[2]  = {r15, 16 + r15};
    const int eLd[2] = {r15, (16 + r15 < kE) ? 16 + r15 : kE - 1};

    f16x4 bf[4][2];                      // B-frags: lane holds B[4g+j][e]
    #pragma unroll
    for (int l = 0; l < 4; ++l)
        #pragma unroll
        for (int n = 0; n < 2; ++n) {
            f32x4 v = *reinterpret_cast<const f32x4*>(
                k1 + ((size_t)(eLd[n] * 4 + l) * kNV + 4 * g));
            f16x4 h;
            h[0] = (_Float16)v[0]; h[1] = (_Float16)v[1];
            h[2] = (_Float16)v[2]; h[3] = (_Float16)v[3];
            bf[l][n] = h;
        }
    f32x4 kq[2][4];                      // {A, B, dA, dB} per (n, j4)
    #pragma unroll
    for (int n = 0; n < 2; ++n)
        #pragma unroll
        for (int j4 = 0; j4 < 4; ++j4) {
            f32x4 c = *reinterpret_cast<const f32x4*>(
                k2 + (size_t)eLd[n] * kNV + 4 * j4);
            kq[n][j4] = (f32x4){c[0], c[2], c[1] - c[0], c[3] - c[2]};
        }

    // ---------------- phase 0: stage calibration tables ----------------
    {   // kp search rows (padded): +INF sentinel at k=15
        int d = tid >> 4, k = tid & 15;
        sKp[d * kKpS + k] = (k == 15) ? __builtin_inff() : cal_kp[tid];
    }
    if (tid < kD * 15) {   // affine entries {slope, intercept}
        int d = tid / 15;
        int k = tid - d * 15;
        float kp0 = cal_kp[d * kK + k];
        float kp1 = cal_kp[d * kK + k + 1];
        float v0  = cal_vals[d * kK + k];
        float v1  = cal_vals[d * kK + k + 1];
        float dxv = kp1 - kp0;
        float slope = (dxv > 0.0f) ? (v1 - v0) / dxv : 0.0f;
        sAff[d * kAffS + k] = (f32x2){slope, fmaf(-slope, kp0, v0)};
    }

    __syncthreads();   // the ONLY block-wide barrier

    // ---------------- tile loop (2 tiles, x prefetched) ----------------
    const int rowTile0 = blockIdx.x * (kRPT * kTPB);
    f32x4 xin = *reinterpret_cast<const f32x4*>(
        x + (size_t)(rowTile0 + wv * 16 + r15) * kD + 4 * q);

    for (int t = 0; t < kTPB; ++t) {
        const int rowBase = rowTile0 + t * kRPT + wv * 16;
        f32x4 xcur = xin;
        if (t + 1 < kTPB)
            xin = *reinterpret_cast<const f32x4*>(
                x + (size_t)(rowTile0 + (t + 1) * kRPT + wv * 16 + r15) * kD + 4 * q);

        // ---- calibrate features 4q..4q+3 of row r15 (binary search) ----
        float xc[4];
        #pragma unroll
        for (int i = 0; i < 4; ++i) {
            const int d = 4 * q + i;
            const float xv = xcur[i];
            const float* kpb = &sKp[d * kKpS];
            int j = 0;
            #pragma unroll
            for (int s = 8; s >= 1; s >>= 1) {
                float kps = kpb[j + s];
                j = (xv >= kps) ? j + s : j;
            }
            f32x2 ent = sAff[d * kAffS + j];      // {slope, intercept}
            xc[i] = fminf(fmaxf(fmaf(ent[0], xv, ent[1]), 0.0f), 1.0f);
        }

        // ---- multilinear corner weights for lattice q (dim0 = MSB) ----
        float wf[16];
        {
            float a = xc[0], b = xc[1], c = xc[2], d = xc[3];
            float t2[2] = {1.0f - a, a};
            float t4[4];
            #pragma unroll
            for (int j = 0; j < 2; ++j) { t4[2*j] = t2[j]*(1.0f-b); t4[2*j+1] = t2[j]*b; }
            float t8[8];
            #pragma unroll
            for (int j = 0; j < 4; ++j) { t8[2*j] = t4[j]*(1.0f-c); t8[2*j+1] = t4[j]*c; }
            #pragma unroll
            for (int j = 0; j < 8; ++j) { wf[2*j] = t8[j]*(1.0f-d); wf[2*j+1] = t8[j]*d; }
        }

        // ---- A-frag exchange via wave-private padded sW ----
        #pragma unroll
        for (int gg = 0; gg < 4; ++gg) {
            f16x4 v;
            v[0] = (_Float16)wf[4*gg+0]; v[1] = (_Float16)wf[4*gg+1];
            v[2] = (_Float16)wf[4*gg+2]; v[3] = (_Float16)wf[4*gg+3];
            sW[(wv * 4 + q) * kWS + r15 + 16 * gg] = v;
        }
        asm volatile("s_waitcnt lgkmcnt(0)" ::: "memory");   // wave-local fence

        f16x4 af[4];
        #pragma unroll
        for (int l = 0; l < 4; ++l) af[l] = sW[(wv * 4 + l) * kWS + lane];

        // ---- MFMA layer-1 + packed layer-2 epilogue ----
        #pragma unroll
        for (int n = 0; n < 2; ++n) {
            f32x4 acc[4];
            #pragma unroll
            for (int l = 0; l < 4; ++l)
                acc[l] = __builtin_amdgcn_mfma_f32_16x16x16f16(
                    af[l], bf[l][n], (f32x4){0.f, 0.f, 0.f, 0.f}, 0, 0, 0);

            f32x2 h3a = clamp01((f32x2){acc[3][0], acc[3][1]});
            f32x2 h3b = clamp01((f32x2){acc[3][2], acc[3][3]});
            f32x2 h2a = clamp01((f32x2){acc[2][0], acc[2][1]});
            f32x2 h2b = clamp01((f32x2){acc[2][2], acc[2][3]});

            f32x2 v4a[4], v4b[4];
            #pragma unroll
            for (int j4 = 0; j4 < 4; ++j4) {
                f32x4 kv = kq[n][j4];             // {A, B, dA, dB} in regs
                f32x2 a0 = fma2s(h3a, kv[2], kv[0]);
                f32x2 b0 = fma2s(h3a, kv[3], kv[1]);
                v4a[j4]  = fma2(h2a, b0 - a0, a0);
                f32x2 a1 = fma2s(h3b, kv[2], kv[0]);
                f32x2 b1 = fma2s(h3b, kv[3], kv[1]);
                v4b[j4]  = fma2(h2b, b1 - a1, a1);
            }

            const int e = eN[n];
            #pragma unroll
            for (int p = 0; p < 2; ++p) {
                f32x2 h1 = clamp01((f32x2){acc[1][2*p], acc[1][2*p+1]});
                f32x2 h0 = clamp01((f32x2){acc[0][2*p], acc[0][2*p+1]});
                const f32x2* v4 = (p == 0) ? v4a : v4b;   // unrolled select
                f32x2 w0 = fma2(h1, v4[1] - v4[0], v4[0]);
                f32x2 w1 = fma2(h1, v4[3] - v4[2], v4[2]);
                f32x2 o  = fma2(h0, w1 - w0, w0);
                if (e < kE) {   // exec-masked store (row=4q+2p(+1), col=e)
                    size_t r0 = (size_t)(rowBase + q * 4 + 2 * p);
                    out[r0 * kE + e]       = o[0];
                    out[(r0 + 1) * kE + e] = o[1];
                }
            }
        }
    }
}

extern "C" void kernel_launch(void* const* d_in, const int* in_sizes, int n_in,
                              void* d_out, int out_size, void* d_ws, size_t ws_size,
                              hipStream_t stream) {
    const float* x        = (const float*)d_in[0];
    const float* cal_kp   = (const float*)d_in[1];
    const float* cal_vals = (const float*)d_in[2];
    const float* k1       = (const float*)d_in[3];
    const float* k2       = (const float*)d_in[4];
    float* out = (float*)d_out;

    hipLaunchKernelGGL(lattice_fwd, dim3(131072 / (kRPT * kTPB)), dim3(kThreads),
                       0, stream, x, cal_kp, cal_vals, k1, k2, out);
}